// Round 1
// baseline (105.532 us; speedup 1.0000x reference)
//
#include <hip/hip_runtime.h>

// Problem constants (match reference setup_inputs)
#define BATCH 8
#define CHN   64
#define GRP   8
#define CG    8      // CHN / GRP
#define HH    128
#define WW    128
#define HW    (HH * WW)   // 16384
// w shape: (B, G, 1, 9, H, W); x/out shape: (B, C, H, W), all fp32.

// One block per (b, g, row-pair). 256 threads = 8 channels x 32 quads.
// Each thread: one channel, one aligned float4 quad, 2 output rows.
// Weights (9 taps x 2 rows x 128 cols = 9 KB) staged once into LDS and
// broadcast-read by all 8 channel-threads -> w HBM traffic stays 1x while
// thread count rises 8x (1M threads, 4096 blocks, ~6 waves/SIMD resident).
__global__ __launch_bounds__(256, 6) void ska_small_kernel(
    const float* __restrict__ x,
    const float* __restrict__ wgt,
    float* __restrict__ out)
{
    __shared__ __align__(16) float lds_w[9][2][WW];   // 9216 B

    const int bid = blockIdx.x;
    const int h2 = bid & 63;          // row-pair index
    const int g  = (bid >> 6) & 7;
    const int b  = bid >> 9;
    const int h0 = h2 * 2;            // even, 0..126
    const int h1 = h0 + 1;            // odd, 1..127

    const int t  = threadIdx.x;
    const int q  = t & 31;            // quad index within row
    const int cg = t >> 5;            // channel within group
    const int w0 = q * 4;             // aligned float4 column

    // Clamped outer row indices (out-of-range rows are weight-masked to zero).
    const int hm = (h0 > 0)      ? h0 - 1 : h0;
    const int hp = (h1 < HH - 1) ? h1 + 1 : h1;

    // ---- issue the 4 x-row loads FIRST: independent of LDS staging, their
    // HBM latency hides under the weight staging + barrier.
    const float* xc = x + (size_t)(b * CHN + g * CG + cg) * HW + w0;
    const float4 rm = *(const float4*)(xc + (size_t)hm * WW);
    const float4 r0 = *(const float4*)(xc + (size_t)h0 * WW);
    const float4 r1 = *(const float4*)(xc + (size_t)h1 * WW);
    const float4 rp = *(const float4*)(xc + (size_t)hp * WW);

    // ---- stage 9x2x128 weights into LDS, folding the vertical-pad mask.
    // Rows h0,h1 are adjacent in memory: per tap k this is one contiguous
    // 256-float (1 KB) segment -> 9 fully-coalesced 256-lane loads.
    {
        const float* wsrc = wgt + ((size_t)(b * GRP + g) * 9) * HW + (size_t)h0 * WW;
        const int  r    = t >> 7;                       // row within pair (0/1)
        const bool ktop = (h0 == 0)      && (r == 0);   // tap-row 0 of image row 0
        const bool kbot = (h1 == HH - 1) && (r == 1);   // tap-row 2 of image row 127
#pragma unroll
        for (int k = 0; k < 9; ++k) {
            float v = wsrc[(size_t)k * HW + t];
            if ((ktop && k < 3) || (kbot && k >= 6)) v = 0.f;
            ((float*)lds_w)[k * 256 + t] = v;
        }
    }
    __syncthreads();

    // Horizontal halo via neighbor-lane shuffle; mask the image pad columns.
    // Wave = 2 channels x 32 quads; the lane-32 crossing has q==0/q==31 so the
    // cross-channel shuffle is masked by mL/mR exactly like the pad columns.
    const float mL = (q > 0)  ? 1.0f : 0.0f;
    const float mR = (q < 31) ? 1.0f : 0.0f;

    // 6-wide row windows: [left, v.x, v.y, v.z, v.w, right] for 4 rows
    float win[4][6];
    win[0][1] = rm.x; win[0][2] = rm.y; win[0][3] = rm.z; win[0][4] = rm.w;
    win[1][1] = r0.x; win[1][2] = r0.y; win[1][3] = r0.z; win[1][4] = r0.w;
    win[2][1] = r1.x; win[2][2] = r1.y; win[2][3] = r1.z; win[2][4] = r1.w;
    win[3][1] = rp.x; win[3][2] = rp.y; win[3][3] = rp.z; win[3][4] = rp.w;
    win[0][0] = __shfl_up(rm.w, 1) * mL;
    win[1][0] = __shfl_up(r0.w, 1) * mL;
    win[2][0] = __shfl_up(r1.w, 1) * mL;
    win[3][0] = __shfl_up(rp.w, 1) * mL;
    win[0][5] = __shfl_down(rm.x, 1) * mR;
    win[1][5] = __shfl_down(r0.x, 1) * mR;
    win[2][5] = __shfl_down(r1.x, 1) * mR;
    win[3][5] = __shfl_down(rp.x, 1) * mR;

    float4 acc0 = make_float4(0.f, 0.f, 0.f, 0.f);  // output row h0: rows m,0,1
    float4 acc1 = make_float4(0.f, 0.f, 0.f, 0.f);  // output row h1: rows 0,1,p
#pragma unroll
    for (int ki = 0; ki < 3; ++ki) {
#pragma unroll
        for (int kj = 0; kj < 3; ++kj) {
            // broadcast across the 8 channel-threads (same address), stride-16B
            // across quads -> conflict-free b128 reads.
            const float4 wv0 = *(const float4*)&lds_w[ki * 3 + kj][0][w0];
            const float4 wv1 = *(const float4*)&lds_w[ki * 3 + kj][1][w0];
            acc0.x = fmaf(win[ki    ][0 + kj], wv0.x, acc0.x);
            acc0.y = fmaf(win[ki    ][1 + kj], wv0.y, acc0.y);
            acc0.z = fmaf(win[ki    ][2 + kj], wv0.z, acc0.z);
            acc0.w = fmaf(win[ki    ][3 + kj], wv0.w, acc0.w);
            acc1.x = fmaf(win[ki + 1][0 + kj], wv1.x, acc1.x);
            acc1.y = fmaf(win[ki + 1][1 + kj], wv1.y, acc1.y);
            acc1.z = fmaf(win[ki + 1][2 + kj], wv1.z, acc1.z);
            acc1.w = fmaf(win[ki + 1][3 + kj], wv1.w, acc1.w);
        }
    }

    float* oc = out + (size_t)(b * CHN + g * CG + cg) * HW + (size_t)h0 * WW + w0;
    *(float4*)(oc)      = acc0;
    *(float4*)(oc + WW) = acc1;
}

extern "C" void kernel_launch(void* const* d_in, const int* in_sizes, int n_in,
                              void* d_out, int out_size, void* d_ws, size_t ws_size,
                              hipStream_t stream) {
    const float* x = (const float*)d_in[0];
    const float* w = (const float*)d_in[1];
    float* out = (float*)d_out;

    // one block per (b, g, row-pair): 8*8*64 = 4096 blocks of 256 threads
    const int grid = BATCH * GRP * (HH / 2);
    ska_small_kernel<<<grid, 256, 0, stream>>>(x, w, out);
}